// Round 1
// 567.606 us; speedup vs baseline: 1.1455x; 1.1455x over previous
//
#include <hip/hip_runtime.h>

static constexpr int B = 32;
static constexpr int R = 64;
static constexpr int L = 4096;
static constexpr int H = 768;

// K0: normalize span (i32 or i64) and mask (bool8 / i32 / i64) into ws.
// (Earlier rounds proved both are i32 on this harness; kept as cheap insurance.)
__global__ void k_norm(const unsigned* __restrict__ span_raw,
                       const unsigned* __restrict__ mask_raw,
                       int* __restrict__ spanw, int* __restrict__ maskw) {
  int t = threadIdx.x;
  __shared__ int f_span64, f_mask8, f_mask64;
  if (t == 0) { f_span64 = 1; f_mask8 = 0; f_mask64 = 1; }
  __syncthreads();
  for (int i = t; i < B * R * 2; i += 256)
    if ((i & 1) && span_raw[i] != 0u) atomicAnd(&f_span64, 0);
  for (int i = t; i < (B * R) / 4; i += 256) {
    unsigned w = mask_raw[i];
    if (w > 1u) atomicOr(&f_mask8, 1);
    if ((i & 1) && w != 0u) atomicAnd(&f_mask64, 0);
  }
  __syncthreads();
  int s64 = f_span64, m8 = f_mask8, m64 = f_mask64;
  for (int i = t; i < B * R * 2; i += 256)
    spanw[i] = (int)(s64 ? span_raw[2 * i] : span_raw[i]);
  if (m8) {
    const unsigned char* bp = (const unsigned char*)mask_raw;
    for (int i = t; i < B * R; i += 256) maskw[i] = bp[i];
  } else if (m64) {
    for (int i = t; i < B * R; i += 256) maskw[i] = (int)mask_raw[2 * i];
  } else {
    const int* ip = (const int*)mask_raw;
    for (int i = t; i < B * R; i += 256) maskw[i] = ip[i];
  }
}

// K1: u[b][h] = sum_k W[h][k] * ans[b][k]
__global__ void k_u(const float* __restrict__ ans,
                    const float* __restrict__ W,
                    float* __restrict__ u) {
  int b = blockIdx.x;
  int h = blockIdx.y * 256 + threadIdx.x;
  __shared__ float a_s[H];
  for (int k = threadIdx.x; k < H; k += 256) a_s[k] = ans[b * H + k];
  __syncthreads();
  const float4* wrow = reinterpret_cast<const float4*>(W + (size_t)h * H);
  float acc = 0.f;
  #pragma unroll 4
  for (int k4 = 0; k4 < H / 4; k4++) {
    float4 w = wrow[k4];
    const float* a = a_s + k4 * 4;
    acc += w.x * a[0] + w.y * a[1] + w.z * a[2] + w.w * a[3];
  }
  u[b * H + h] = acc;
}

// K2: d[b][l] = hid[b][l][:] . u[b][:]  — the single streaming pass over hid.
// One wave per row; 4 rows (same b) per 256-thread block; float4 coalesced.
__global__ __launch_bounds__(256) void k_dot(const float* __restrict__ hid,
                                             const float* __restrict__ u,
                                             float* __restrict__ d) {
  int row  = blockIdx.x * 4 + (threadIdx.x >> 6);
  int lane = threadIdx.x & 63;
  int b    = blockIdx.x >> 10;           // (blockIdx.x*4)/L, L=4096
  __shared__ float u_s[H];
  for (int k = threadIdx.x; k < H; k += 256) u_s[k] = u[b * H + k];
  __syncthreads();
  const float4* p = reinterpret_cast<const float4*>(hid + (size_t)row * H);
  float acc = 0.f;
  #pragma unroll
  for (int i = 0; i < 3; i++) {           // H/4 = 192 float4 = 64 lanes x 3
    int j = lane + 64 * i;
    float4 v = p[j];
    const float* uu = u_s + 4 * j;
    acc += v.x * uu[0] + v.y * uu[1] + v.z * uu[2] + v.w * uu[3];
  }
  #pragma unroll
  for (int o = 32; o > 0; o >>= 1) acc += __shfl_xor(acc, o, 64);
  if (lane == 0) d[row] = acc;
}

// K3: per batch — scalar inclusive scan of d[b][0..L) in LDS, then
// score lookup (csd[e]-csd[s])/len + bias, then softmax. One block per b.
__global__ __launch_bounds__(256) void k_finish(const float* __restrict__ d,
                                                const int* __restrict__ span,
                                                const int* __restrict__ mask,
                                                const float* __restrict__ bias,
                                                float* __restrict__ out) {
  int b = blockIdx.x;
  int t = threadIdx.x;
  int lane = t & 63, wid = t >> 6;
  __shared__ float csd[L + 1];
  __shared__ float wsum[4];

  // 16 elements per thread (4x float4), thread-local sum
  const float4* db4 = reinterpret_cast<const float4*>(d + (size_t)b * L) + t * 4;
  float vals[16];
  float s = 0.f;
  #pragma unroll
  for (int q = 0; q < 4; q++) {
    float4 v = db4[q];
    vals[4 * q + 0] = v.x; vals[4 * q + 1] = v.y;
    vals[4 * q + 2] = v.z; vals[4 * q + 3] = v.w;
    s += v.x + v.y + v.z + v.w;
  }
  // inclusive wave scan of thread sums
  float ss = s;
  #pragma unroll
  for (int o = 1; o < 64; o <<= 1) {
    float n = __shfl_up(ss, o, 64);
    if (lane >= o) ss += n;
  }
  if (lane == 63) wsum[wid] = ss;
  __syncthreads();
  float base = 0.f;
  #pragma unroll
  for (int w = 0; w < 4; w++) if (w < wid) base += wsum[w];
  float run = base + ss - s;              // exclusive prefix for this thread
  #pragma unroll
  for (int i = 0; i < 16; i++) { run += vals[i]; csd[t * 16 + 1 + i] = run; }
  if (t == 0) csd[0] = 0.f;
  __syncthreads();

  if (t < R) {                            // wave 0 only
    int br = b * R + t;
    float sc;
    if (mask[br] == 0) {
      sc = -__builtin_huge_valf();
    } else {
      int s0 = span[br * 2], e0 = span[br * 2 + 1];
      int dl = e0 - s0;
      sc = (csd[e0] - csd[s0]) / (float)(dl > 1 ? dl : 1) + bias[0];
    }
    float m = sc;
    #pragma unroll
    for (int o = 32; o > 0; o >>= 1) m = fmaxf(m, __shfl_xor(m, o, 64));
    float ex = __expf(sc - m);
    float sm = ex;
    #pragma unroll
    for (int o = 32; o > 0; o >>= 1) sm += __shfl_xor(sm, o, 64);
    out[br] = ex / sm;
  }
}

extern "C" void kernel_launch(void* const* d_in, const int* in_sizes, int n_in,
                              void* d_out, int out_size, void* d_ws, size_t ws_size,
                              hipStream_t stream) {
  // Remap by element count (all six are distinct) for ordering robustness.
  const void *p_ans = d_in[0], *p_hid = d_in[1], *p_span = d_in[2],
             *p_mask = d_in[3], *p_W = d_in[4], *p_b = d_in[5];
  for (int i = 0; i < n_in; i++) {
    switch (in_sizes[i]) {
      case B * H:     p_ans  = d_in[i]; break;   // 24576
      case B * L * H: p_hid  = d_in[i]; break;   // 100663296
      case B * R * 2: p_span = d_in[i]; break;   // 4096
      case B * R:     p_mask = d_in[i]; break;   // 2048
      case H * H:     p_W    = d_in[i]; break;   // 589824
      case 1:         p_b    = d_in[i]; break;
    }
  }
  const float*    ans  = (const float*)p_ans;
  const float*    hid  = (const float*)p_hid;
  const unsigned* span = (const unsigned*)p_span;
  const unsigned* mask = (const unsigned*)p_mask;
  const float*    W    = (const float*)p_W;
  const float*    bias = (const float*)p_b;

  float* d_buf  = (float*)d_ws;                   // B*L
  float* u      = d_buf + (size_t)B * L;          // B*H
  int*   maskw  = (int*)(u + (size_t)B * H);      // B*R
  int*   spanw  = maskw + B * R;                  // B*R*2
  // total ws need: ~640 KB (<< provided workspace)

  k_norm<<<1, 256, 0, stream>>>(span, mask, spanw, maskw);
  k_u<<<dim3(B, H / 256), 256, 0, stream>>>(ans, W, u);
  k_dot<<<B * L / 4, 256, 0, stream>>>(hid, u, d_buf);
  k_finish<<<B, 256, 0, stream>>>(d_buf, spanw, maskw, bias, (float*)d_out);
}